// Round 6
// baseline (209.006 us; speedup 1.0000x reference)
//
#include <hip/hip_runtime.h>
#include <hip/hip_bf16.h>
#include <stdint.h>
#include <stddef.h>

// GlobalLSTMCell — f32 in/out, bf16 MFMA compute, SINGLE fused kernel.
//   ifo = sigmoid(x@W_ifo_x + b_ifo_x + h@W_ifo_h + b_ifo_h); i,f,o = split
//   a   = tanh(x@W_b_x + b_b_x + h@W_b_h + b_b_h)
//   c   = i*a + f*c_prev ; h = o*tanh(c) ; out = [h ; c] f32.
// R9: pack_all DELETED. The GEMM reg-stages A directly from x/h f32 (cvt,
//     no transpose needed) and B directly from W f32 (transpose done in the
//     ds_write addressing). R6's verified 8-phase barrier ledger kept:
//     commits (cvt+ds_write) sit in the old gl2lds slots; issues run 2
//     phases early (sets SO/SE, reissued in place) so HBM latency hides
//     under 2 MFMA phases. ds_writes published via lgkmcnt(0) BEFORE frag
//     reads (reads stay outstanding). Swizzle f(n)=(n>>2)&3 both sides:
//     reads + A-writes 2-way (free), B-transpose b64 writes 8-way on 4
//     instr/thread/half (~1% of K-tile). Same-n0 blocks share an XCD with
//     linear dispatch -> W f32 re-reads are L2-served.

#define BATCH 4096
#define FEAT  1024
#define HID   1024
#define NCAT  4096
#define KCAT  2048

typedef __attribute__((ext_vector_type(8))) __bf16 bf16x8;
typedef __attribute__((ext_vector_type(4))) float  floatx4;

__device__ __forceinline__ unsigned short f2bf(float f) {
    __hip_bfloat16 b = __float2bfloat16(f);
    return *reinterpret_cast<unsigned short*>(&b);
}

// ---------------- fused pack+GEMM+LSTM (256x256, BK=64, 8-phase) ----------------
#define BM 256
#define BN 256
#define BK 64
#define NIT 16         // 16 iterations x 2 K-tiles = KCAT/BK = 32
#define HALF 8192      // u16 per half-region: 256 rows x 4 chunks x 8 u16 (16 KB)

// LDS: A(par,ks) at (par*2+ks)*HALF ; B(par,ks) at 32768 + (par*2+ks)*HALF.
#define A_OFF(PAR, KS) (((PAR) * 2 + (KS)) * HALF)
#define B_OFF(PAR, KS) (32768 + ((PAR) * 2 + (KS)) * HALF)

// ---- staging macros (per-thread maps precomputed in kernel body) ----
// A half-tile [256m x 32k]: thread -> m = t>>1, 16 consecutive k at (t&1)*16.
#define ISSUE_A(S, KT, KS) {                                                    \
    const float* s_ = ((KT) < 16) ? (xrow + (KT) * 64 + (KS) * 32)              \
                                  : (hrow + ((KT) - 16) * 64 + (KS) * 32);      \
    S[0] = *(const floatx4*)(s_);      S[1] = *(const floatx4*)(s_ + 4);        \
    S[2] = *(const floatx4*)(s_ + 8);  S[3] = *(const floatx4*)(s_ + 12); }

#define COMMIT_A(S, PAR, KS) {                                                  \
    union { unsigned short u[8]; uint4 v; } w0_, w1_;                           \
    _Pragma("unroll")                                                           \
    for (int e_ = 0; e_ < 4; ++e_) {                                            \
        w0_.u[e_] = f2bf(S[0][e_]); w0_.u[4 + e_] = f2bf(S[1][e_]);             \
        w1_.u[e_] = f2bf(S[2][e_]); w1_.u[4 + e_] = f2bf(S[3][e_]); }           \
    *(uint4*)&lds[A_OFF(PAR, KS) + am * 32 + as0 * 8] = w0_.v;                  \
    *(uint4*)&lds[A_OFF(PAR, KS) + am * 32 + as1 * 8] = w1_.v; }

// B half-tile [256n x 32k] from W[k][q]: thread -> np4 = (t&63)*4 (4 cols),
// k4 = (t>>6)*4 (4 rows). Transpose happens in COMMIT_B's write addressing.
#define ISSUE_B(S, KT, KS) {                                                    \
    int kg_ = (KT) * 64 + (KS) * 32 + bk4;                                      \
    const float* s_ = (kg_ < 1024) ? (bxcol + (size_t)kg_ * bstride)            \
                                   : (bhcol + (size_t)(kg_ - 1024) * bstride);  \
    S[0] = *(const floatx4*)(s_);                                               \
    S[1] = *(const floatx4*)(s_ + bstride);                                     \
    S[2] = *(const floatx4*)(s_ + 2 * (size_t)bstride);                         \
    S[3] = *(const floatx4*)(s_ + 3 * (size_t)bstride); }

#define COMMIT_B(S, PAR, KS) {                                                  \
    _Pragma("unroll")                                                           \
    for (int c_ = 0; c_ < 4; ++c_) {                                            \
        union { unsigned short u[4]; uint2 v; } w_;                             \
        w_.u[0] = f2bf(S[0][c_]); w_.u[1] = f2bf(S[1][c_]);                     \
        w_.u[2] = f2bf(S[2][c_]); w_.u[3] = f2bf(S[3][c_]);                     \
        *(uint2*)&lds[B_OFF(PAR, KS) + (bnp4 + c_) * 32 + bswz * 8 + bsub * 4]  \
            = w_.v; } }

#define LOAD_BB(PAR, KS)                                                        \
    _Pragma("unroll")                                                           \
    for (int g_ = 0; g_ < 4; ++g_)                                              \
        bb[g_] = *(const bf16x8*)&lds[B_OFF(PAR, KS) + (wn + g_ * 16 + lm) * 32 + cr];
#define LOAD_AA(PAR, KS, IQ)                                                    \
    _Pragma("unroll")                                                           \
    for (int ii = 0; ii < 4; ++ii)                                              \
        aa[ii] = *(const bf16x8*)&lds[A_OFF(PAR, KS) + (wm + (IQ) * 64 + ii * 16 + lm) * 32 + cr];
#define MFMA16(IQ)                                                              \
    __builtin_amdgcn_s_setprio(1);                                              \
    _Pragma("unroll")                                                           \
    for (int ii = 0; ii < 4; ++ii)                                              \
        _Pragma("unroll")                                                       \
        for (int g_ = 0; g_ < 4; ++g_)                                          \
            acc[(IQ) * 4 + ii][g_] = __builtin_amdgcn_mfma_f32_16x16x32_bf16(   \
                aa[ii], bb[g_], acc[(IQ) * 4 + ii][g_], 0, 0, 0);               \
    __builtin_amdgcn_s_setprio(0);
#define BAR __builtin_amdgcn_s_barrier();
#define DRAIN asm volatile("s_waitcnt lgkmcnt(0)" ::: "memory");

__global__ __launch_bounds__(512, 2)
void lstm_one(const float* __restrict__ x, const float* __restrict__ h,
              const float* __restrict__ c_prev,
              const float* __restrict__ Wix, const float* __restrict__ Wih,
              const float* __restrict__ Wbx, const float* __restrict__ Wbh,
              const float* __restrict__ bix, const float* __restrict__ bih,
              const float* __restrict__ bbx, const float* __restrict__ bbh,
              float* __restrict__ out_h, float* __restrict__ out_c) {
    __shared__ unsigned short lds[65536];       // 128 KiB
    const int t    = threadIdx.x;
    const int lane = t & 63;
    const int wid  = t >> 6;                    // 0..7
    const int wm   = (wid >> 2) * 128;          // M-half of block tile
    const int wn   = (wid & 3) * 64;            // N-quarter (one gate-group)
    const int m0   = blockIdx.y * BM;
    const int n0   = blockIdx.x * BN;
    const int lm   = lane & 15;
    const int lk   = lane >> 4;                 // desired k-chunk (0..3)
    const int cr   = (lk ^ ((lm >> 2) & 3)) * 8;  // swizzled read slot (u16)

    // ---- A staging map ----
    const int am   = t >> 1;                    // m row 0..255
    const float* xrow = x + (size_t)(m0 + am) * FEAT + (t & 1) * 16;
    const float* hrow = h + (size_t)(m0 + am) * HID  + (t & 1) * 16;
    const int ac0  = (t & 1) * 2;               // first chunk of this thread
    const int aswz = (am >> 2) & 3;
    const int as0  = ac0 ^ aswz;
    const int as1  = (ac0 + 1) ^ aswz;

    // ---- B staging map (np = GEMM B-row; q = source W column) ----
    // np = (j>>4)*64 + g*16 + (j&15): g = gate, j = within-gate column.
    const int bnp4 = (t & 63) * 4;              // B rows np4..np4+3
    const int bk4  = (t >> 6) * 4;              // k rows (within 32-k half)
    const int bg   = (bnp4 >> 4) & 3;
    const int bj   = (((n0 + bnp4) >> 6) << 4) | (bnp4 & 15);
    const int bq   = (bg < 3) ? bg * 1024 + bj : bj;
    const int bstride = (bg < 3) ? 3 * HID : HID;
    const float* bxcol = ((bg < 3) ? Wix : Wbx) + bq;
    const float* bhcol = ((bg < 3) ? Wih : Wbh) + bq;
    const int bswz = (bk4 >> 3) ^ ((bnp4 >> 2) & 3);
    const int bsub = (bk4 >> 2) & 1;

    floatx4 acc[8][4];
#pragma unroll
    for (int i = 0; i < 8; ++i)
#pragma unroll
        for (int g = 0; g < 4; ++g) acc[i][g] = (floatx4){0.f, 0.f, 0.f, 0.f};

    floatx4 SO[4], SE[4];                       // in-flight staging reg sets
    bf16x8 aa[4], bb[4];

    // ---- prologue: K0 both halves + K1-ks0 committed; K1-ks1 issued ----
    ISSUE_A(SO, 0, 0) ISSUE_B(SE, 0, 0)
    COMMIT_A(SO, 0, 0) COMMIT_B(SE, 0, 0)
    ISSUE_A(SO, 0, 1) ISSUE_B(SE, 0, 1)
    COMMIT_A(SO, 0, 1) COMMIT_B(SE, 0, 1)
    ISSUE_A(SO, 1, 0) ISSUE_B(SE, 1, 0)
    COMMIT_A(SO, 1, 0) COMMIT_B(SE, 1, 0)
    ISSUE_A(SO, 1, 1)                           // -> commit at P1
    ISSUE_B(SE, 1, 1)                           // -> commit at P2
    DRAIN
    BAR

    for (int it = 0; it < NIT; ++it) {
        const int k2 = 2 * it + 2, k3 = 2 * it + 3;
        const bool more = (it < NIT - 1);

        // P1: commit A(1,1)@k1 | frags(0,0) | issue A(0,0)@k2 | MFMA(0,0,iq0)
        COMMIT_A(SO, 1, 1) DRAIN
        LOAD_BB(0, 0) LOAD_AA(0, 0, 0)
        if (more) ISSUE_A(SO, k2, 0)
        BAR MFMA16(0) BAR
        // P2: commit B(1,1)@k1 | frag | issue B(0,0)@k2 | MFMA(0,0,iq1)
        COMMIT_B(SE, 1, 1) DRAIN
        LOAD_AA(0, 0, 1)
        if (more) ISSUE_B(SE, k2, 0)
        BAR MFMA16(1) BAR
        // P3: commit A(0,0)@k2 | frags(0,1) | issue A(0,1)@k2 | MFMA(0,1,iq0)
        if (more) { COMMIT_A(SO, 0, 0) DRAIN }
        LOAD_BB(0, 1) LOAD_AA(0, 1, 0)
        if (more) ISSUE_A(SO, k2, 1)
        BAR MFMA16(0) BAR
        // P4: commit B(0,0)@k2 | frag | issue B(0,1)@k2 | MFMA(0,1,iq1)
        if (more) { COMMIT_B(SE, 0, 0) DRAIN }
        LOAD_AA(0, 1, 1)
        if (more) ISSUE_B(SE, k2, 1)
        BAR MFMA16(1) BAR
        // P5: commit A(0,1)@k2 | frags(1,0) | issue A(1,0)@k3 | MFMA(1,0,iq0)
        if (more) { COMMIT_A(SO, 0, 1) DRAIN }
        LOAD_BB(1, 0) LOAD_AA(1, 0, 0)
        if (more) ISSUE_A(SO, k3, 0)
        BAR MFMA16(0) BAR
        // P6: commit B(0,1)@k2 | frag | issue B(1,0)@k3 | MFMA(1,0,iq1)
        if (more) { COMMIT_B(SE, 0, 1) DRAIN }
        LOAD_AA(1, 0, 1)
        if (more) ISSUE_B(SE, k3, 0)
        BAR MFMA16(1) BAR
        // P7: commit A(1,0)@k3 | frags(1,1) | issue A(1,1)@k3 | MFMA(1,1,iq0)
        if (more) { COMMIT_A(SO, 1, 0) DRAIN }
        LOAD_BB(1, 1) LOAD_AA(1, 1, 0)
        if (more) ISSUE_A(SO, k3, 1)
        BAR MFMA16(0) BAR
        // P8: commit B(1,0)@k3 | frag | issue B(1,1)@k3 | MFMA(1,1,iq1)
        if (more) { COMMIT_B(SE, 1, 0) DRAIN }
        LOAD_AA(1, 1, 1)
        if (more) ISSUE_B(SE, k3, 1)
        BAR MFMA16(1) BAR
    }

    // ---- LSTM epilogue ----
    // acc[idx][g][r]: m = m0 + wm + idx*16 + (lane>>4)*4 + r,
    //                 gate g at j = ((n0+wn)>>6)*16 + lm.
    const int j  = (((n0 + wn) >> 6) << 4) + lm;
    const float bi = bix[j]           + bih[j];
    const float bf = bix[HID + j]     + bih[HID + j];
    const float bo = bix[2 * HID + j] + bih[2 * HID + j];
    const float ba = bbx[j]           + bbh[j];
#pragma unroll
    for (int i = 0; i < 8; ++i) {
#pragma unroll
        for (int r = 0; r < 4; ++r) {
            int m = m0 + wm + i * 16 + (lk * 4) + r;
            float pi = acc[i][0][r] + bi;
            float pf = acc[i][1][r] + bf;
            float po = acc[i][2][r] + bo;
            float pa = acc[i][3][r] + ba;
            float ig = 1.f / (1.f + __expf(-pi));
            float fg = 1.f / (1.f + __expf(-pf));
            float og = 1.f / (1.f + __expf(-po));
            float av = 2.f / (1.f + __expf(-2.f * pa)) - 1.f;
            float cp = c_prev[(size_t)m * HID + j];
            float cv = ig * av + fg * cp;
            float hv = og * (2.f / (1.f + __expf(-2.f * cv)) - 1.f);
            out_h[(size_t)m * HID + j] = hv;
            out_c[(size_t)m * HID + j] = cv;
        }
    }
}

extern "C" void kernel_launch(void* const* d_in, const int* in_sizes, int n_in,
                              void* d_out, int out_size, void* d_ws, size_t ws_size,
                              hipStream_t stream) {
    const float* x   = (const float*)d_in[0];
    const float* h   = (const float*)d_in[1];
    const float* c   = (const float*)d_in[2];
    const float* Wix = (const float*)d_in[3];
    const float* bix = (const float*)d_in[4];
    const float* Wih = (const float*)d_in[5];
    const float* bih = (const float*)d_in[6];
    const float* Wbx = (const float*)d_in[7];
    const float* bbx = (const float*)d_in[8];
    const float* Wbh = (const float*)d_in[9];
    const float* bbh = (const float*)d_in[10];

    float* out_h = (float*)d_out;
    float* out_c = out_h + (size_t)BATCH * HID;

    lstm_one<<<dim3(NCAT / BN, BATCH / BM), 512, 0, stream>>>(
        x, h, c, Wix, Wih, Wbx, Wbh, bix, bih, bbx, bbh, out_h, out_c);
}